// Round 1
// 1047.176 us; speedup vs baseline: 1.1146x; 1.1146x over previous
//
#include <hip/hip_runtime.h>

// Problem constants
#define NB  16384   // batch
#define MM  64      // memory slots
#define DV  64
#define DK  64
#define DQA 128
#define MD  4096    // MM*DV
#define LDW 4224    // padded row stride (elements) for transposed weights: +256B -> channel rotation

typedef float  floatx4 __attribute__((ext_vector_type(4)));
typedef short  shortx8 __attribute__((ext_vector_type(8)));
typedef unsigned short ushortx4 __attribute__((ext_vector_type(4)));

static __device__ __forceinline__ unsigned short f2bf(float f) {
  union { float f; unsigned int u; } v; v.f = f;
  unsigned int r = v.u + 0x7FFFu + ((v.u >> 16) & 1u);  // RNE
  return (unsigned short)(r >> 16);
}
static __device__ __forceinline__ float bf2f(unsigned short u) {
  union { unsigned int u; float f; } v; v.u = (unsigned int)u << 16; return v.f;
}
static __device__ __forceinline__ float sigm(float x) { return 1.0f / (1.0f + __expf(-x)); }

static __device__ __forceinline__ shortx8 load8bf(const float* p) {
  const float4* p4 = (const float4*)p;
  float4 a = p4[0];
  float4 b = p4[1];
  shortx8 r;
  r[0] = (short)f2bf(a.x); r[1] = (short)f2bf(a.y);
  r[2] = (short)f2bf(a.z); r[3] = (short)f2bf(a.w);
  r[4] = (short)f2bf(b.x); r[5] = (short)f2bf(b.y);
  r[6] = (short)f2bf(b.z); r[7] = (short)f2bf(b.w);
  return r;
}

// ---------------------------------------------------------------------------
// k_tr: transpose+convert  src fp32 [K][N] (row-major, ld=N)  ->  dst bf16 [N][dstld]
// grid (K/64, N/64).
// ---------------------------------------------------------------------------
__global__ __launch_bounds__(256) void k_tr(const float* __restrict__ src,
                                            unsigned short* __restrict__ dst,
                                            int N, int dstld) {
  __shared__ unsigned short T[64 * 72];
  const int k0 = blockIdx.x * 64, n0 = blockIdx.y * 64;
  const int t = threadIdx.x;
#pragma unroll
  for (int i = 0; i < 16; ++i) {
    int idx = t + i * 256, kl = idx >> 6, nl = idx & 63;
    T[kl * 72 + nl] = f2bf(src[(size_t)(k0 + kl) * N + n0 + nl]);
  }
  __syncthreads();
#pragma unroll
  for (int i = 0; i < 16; ++i) {
    int idx = t + i * 256, nl = idx >> 6, kl = idx & 63;
    dst[(size_t)(n0 + nl) * dstld + k0 + kl] = T[kl * 72 + nl];
  }
}

// ---------------------------------------------------------------------------
// K1: write_weight = softmax(control_key @ memory_key^T).  One wave per row.
// ---------------------------------------------------------------------------
__global__ __launch_bounds__(256) void k_ww(const float* __restrict__ ck,
                                            const float* __restrict__ mk,
                                            float* __restrict__ ww) {
  const int t = threadIdx.x;
  const int lane = t & 63;
  const int wv = t >> 6;
  const int b = blockIdx.x * 4 + wv;
  const float4* ck4 = (const float4*)(ck + (size_t)b * DK);
  const float4* mk4 = (const float4*)(mk + (size_t)lane * DK);
  float s = 0.f;
#pragma unroll
  for (int i = 0; i < DK / 4; ++i) {
    float4 a = ck4[i], m = mk4[i];
    s += a.x * m.x + a.y * m.y + a.z * m.z + a.w * m.w;
  }
  float mx = s;
#pragma unroll
  for (int off = 32; off; off >>= 1) mx = fmaxf(mx, __shfl_xor(mx, off, 64));
  float e = __expf(s - mx);
  float sum = e;
#pragma unroll
  for (int off = 32; off; off >>= 1) sum += __shfl_xor(sum, off, 64);
  ww[(size_t)b * MM + lane] = e / sum;
}

// ---------------------------------------------------------------------------
// K2: partial pre-activation of c0:  P[split] = mv @ Wc0  over K-half "split".
// Grid (NB/32, 2), 4 waves: wave (mh=wv&1) rows mh*16, (nq2=wv>>1) cols nq2*64.
// K-chunk order is staggered by blockIdx.x so co-resident blocks hit different
// memory-channel column slices.
// ---------------------------------------------------------------------------
__global__ __launch_bounds__(256) void k_c0(const float* __restrict__ mv,
                                            const unsigned short* __restrict__ WcT,
                                            float* __restrict__ P) {
  __shared__ __align__(16) unsigned short WB[DQA * 136];   // [n<128][k<128 +8]
  const int t = threadIdx.x, lane = t & 63, wv = t >> 6;
  const int quad = lane >> 4, l16 = lane & 15;
  const int mh = wv & 1, nq2 = wv >> 1;
  const int rowbase = blockIdx.x * 32;
  const int split = blockIdx.y;
  const int arow = rowbase + mh * 16 + l16;

  floatx4 acc[4];
#pragma unroll
  for (int nt = 0; nt < 4; ++nt) acc[nt] = (floatx4){0.f, 0.f, 0.f, 0.f};

  for (int c = 0; c < 16; ++c) {
    const int kc = split * 16 + ((c + blockIdx.x) & 15);
    const int kb = kc * 128;
    // A fragments first (global latency overlaps staging)
    shortx8 afr[4];
#pragma unroll
    for (int ks = 0; ks < 4; ++ks)
      afr[ks] = load8bf(mv + (size_t)arow * MD + kb + ks * 32 + quad * 8);
    // stage WcT[:, kb..kb+128) as [n][k] bf16 (pure 16B copies)
#pragma unroll
    for (int i = 0; i < 8; ++i) {
      int idx = t + i * 256;     // 0..2047
      int n = idx >> 4, kbk = idx & 15;
      *(shortx8*)&WB[n * 136 + kbk * 8] =
          *(const shortx8*)(WcT + (size_t)n * LDW + kb + kbk * 8);
    }
    __syncthreads();
#pragma unroll
    for (int nt = 0; nt < 4; ++nt)
#pragma unroll
      for (int ks = 0; ks < 4; ++ks) {
        shortx8 bfr = *(const shortx8*)&WB[(nq2 * 64 + nt * 16 + l16) * 136 + ks * 32 + quad * 8];
        acc[nt] = __builtin_amdgcn_mfma_f32_16x16x32_bf16(afr[ks], bfr, acc[nt], 0, 0, 0);
      }
    __syncthreads();
  }
  float* Pp = P + (size_t)split * NB * DQA;
#pragma unroll
  for (int nt = 0; nt < 4; ++nt) {
    int col = nq2 * 64 + nt * 16 + l16;
#pragma unroll
    for (int r = 0; r < 4; ++r) {
      int row = rowbase + mh * 16 + quad * 4 + r;
      Pp[(size_t)row * DQA + col] = acc[nt][r];
    }
  }
}

// ---------------------------------------------------------------------------
// K2b: combine the two K-halves, apply bias+sigmoid+qa, store bf16 c0.
// ---------------------------------------------------------------------------
__global__ __launch_bounds__(256) void k_c0fin(const float* __restrict__ P,
                                               const float* __restrict__ bc0,
                                               const float* __restrict__ qa,
                                               unsigned short* __restrict__ c0p) {
  const size_t i4 = ((size_t)blockIdx.x * 256 + threadIdx.x) * 4;
  const int col = (int)(i4 & (DQA - 1));
  float4 p0 = *(const float4*)(P + i4);
  float4 p1 = *(const float4*)(P + (size_t)NB * DQA + i4);
  float4 b  = *(const float4*)(bc0 + col);
  float4 q  = *(const float4*)(qa + i4);
  ushortx4 o;
  o[0] = f2bf(q.x * sigm(p0.x + p1.x + b.x));
  o[1] = f2bf(q.y * sigm(p0.y + p1.y + b.y));
  o[2] = f2bf(q.z * sigm(p0.z + p1.z + b.z));
  o[3] = f2bf(q.w * sigm(p0.w + p1.w + b.w));
  *(ushortx4*)(c0p + i4) = o;
}

// ---------------------------------------------------------------------------
// K3: gate1 chunk via MFMA, mp = mv * g1 (fp32) written into d_out.
// Grid (NB/64, MD/128), 256 thr (4 waves, wave wv rows wv*16, all 128 cols).
// ---------------------------------------------------------------------------
__global__ __launch_bounds__(256) void k_g1mp(const float* __restrict__ mv,
                                              const unsigned short* __restrict__ c0p,
                                              const unsigned short* __restrict__ Wm1T,
                                              const float* __restrict__ bm1,
                                              float* __restrict__ mp) {
  __shared__ __align__(16) unsigned short WB[128 * 136];   // [n<128][k<128 +8]
  const int t = threadIdx.x, lane = t & 63, wv = t >> 6;
  const int quad = lane >> 4, l16 = lane & 15;
  const int rowbase = blockIdx.x * 64;
  const int colbase = blockIdx.y * 128;

  // c0 A-fragments (full K=128)
  shortx8 c0fr[4];
#pragma unroll
  for (int ks = 0; ks < 4; ++ks)
    c0fr[ks] = *(const shortx8*)(c0p + (size_t)(rowbase + wv * 16 + l16) * DQA + ks * 32 + quad * 8);

  // stage Wm1T rows [colbase..colbase+128), full K=128
#pragma unroll
  for (int i = 0; i < 8; ++i) {
    int idx = t + i * 256;
    int n = idx >> 4, kbk = idx & 15;
    *(shortx8*)&WB[n * 136 + kbk * 8] =
        *(const shortx8*)(Wm1T + (size_t)(colbase + n) * DQA + kbk * 8);
  }
  __syncthreads();

  floatx4 acc[8];
#pragma unroll
  for (int nt = 0; nt < 8; ++nt) acc[nt] = (floatx4){0.f, 0.f, 0.f, 0.f};
#pragma unroll
  for (int nt = 0; nt < 8; ++nt)
#pragma unroll
    for (int ks = 0; ks < 4; ++ks) {
      shortx8 bfr = *(const shortx8*)&WB[(nt * 16 + l16) * 136 + ks * 32 + quad * 8];
      acc[nt] = __builtin_amdgcn_mfma_f32_16x16x32_bf16(c0fr[ks], bfr, acc[nt], 0, 0, 0);
    }

#pragma unroll
  for (int nt = 0; nt < 8; ++nt) {
    int colg = colbase + nt * 16 + l16;
    float b = bm1[colg];
#pragma unroll
    for (int r = 0; r < 4; ++r) {
      int row = rowbase + wv * 16 + quad * 4 + r;
      float g = sigm(acc[nt][r] + b);
      mp[(size_t)row * MD + colg] = mv[(size_t)row * MD + colg] * g;
    }
  }
}

// ---------------------------------------------------------------------------
// K4: partial S[16384 x 192] = mp @ [WemvT|WzmvT|WamvT]^T over K-half "split".
// Grid (NB/32, 2), 4 waves: rows (wv&1)*16, cols (wv>>1)*96 (6 n-tiles).
// Staggered K-chunk order; padded W3T rows (LDW).
// ---------------------------------------------------------------------------
__global__ __launch_bounds__(256) void k_S(const float* __restrict__ mp,
                                           const unsigned short* __restrict__ W3T,
                                           float* __restrict__ Sg) {
  __shared__ __align__(16) unsigned short WB[192 * 136];   // [n<192][k<128 +8]
  const int t = threadIdx.x, lane = t & 63, wv = t >> 6;
  const int quad = lane >> 4, l16 = lane & 15;
  const int mh = wv & 1, nh2 = wv >> 1;
  const int rowbase = blockIdx.x * 32;
  const int split = blockIdx.y;
  const int arow = rowbase + mh * 16 + l16;

  floatx4 acc[6];
#pragma unroll
  for (int nt = 0; nt < 6; ++nt) acc[nt] = (floatx4){0.f, 0.f, 0.f, 0.f};

  for (int c = 0; c < 16; ++c) {
    const int kc = split * 16 + ((c + blockIdx.x) & 15);
    const int kb = kc * 128;
    shortx8 afr[4];
#pragma unroll
    for (int ks = 0; ks < 4; ++ks)
      afr[ks] = load8bf(mp + (size_t)arow * MD + kb + ks * 32 + quad * 8);
#pragma unroll
    for (int i = 0; i < 12; ++i) {
      int idx = t + i * 256;     // 0..3071
      int n = idx >> 4, kbk = idx & 15;
      *(shortx8*)&WB[n * 136 + kbk * 8] =
          *(const shortx8*)(W3T + (size_t)n * LDW + kb + kbk * 8);
    }
    __syncthreads();
#pragma unroll
    for (int nt = 0; nt < 6; ++nt)
#pragma unroll
      for (int ks = 0; ks < 4; ++ks) {
        shortx8 bfr = *(const shortx8*)&WB[(nh2 * 96 + nt * 16 + l16) * 136 + ks * 32 + quad * 8];
        acc[nt] = __builtin_amdgcn_mfma_f32_16x16x32_bf16(afr[ks], bfr, acc[nt], 0, 0, 0);
      }
    __syncthreads();
  }
  float* Sp = Sg + (size_t)split * NB * 192;
#pragma unroll
  for (int nt = 0; nt < 6; ++nt) {
    int col = nh2 * 96 + nt * 16 + l16;
#pragma unroll
    for (int r = 0; r < 4; ++r) {
      int row = rowbase + mh * 16 + quad * 4 + r;
      Sp[(size_t)row * 192 + col] = acc[nt][r];
    }
  }
}

// ---------------------------------------------------------------------------
// K5: finalize erase / zt / add  (small GEMMs, fp32 VALU).  Block = 4 rows x 64.
// Sums the two K-half partials of S.
// ---------------------------------------------------------------------------
__global__ __launch_bounds__(256) void k_eza(const unsigned short* __restrict__ c0p,
                                             const float* __restrict__ Sg,
                                             const float* __restrict__ We,
                                             const float* __restrict__ be,
                                             const float* __restrict__ Wz,
                                             const float* __restrict__ bz,
                                             const float* __restrict__ Wza,
                                             const float* __restrict__ bza,
                                             const float* __restrict__ bemv,
                                             const float* __restrict__ bzmv,
                                             const float* __restrict__ bamv,
                                             float* __restrict__ eg,
                                             float* __restrict__ ag) {
  __shared__ float ztl[4][64];
  const int t = threadIdx.x;
  const int j = t & 63;
  const int r = t >> 6;
  const int b = blockIdx.x * 4 + r;
  const unsigned short* c0r = c0p + (size_t)b * DQA;
  float ae = 0.f, az = 0.f;
#pragma unroll 8
  for (int k = 0; k < DQA; ++k) {
    float cv = bf2f(c0r[k]);
    ae += cv * We[k * DV + j];
    az += cv * Wz[k * DV + j];
  }
  const float* Sr0 = Sg + (size_t)b * 192;
  const float* Sr1 = Sg + (size_t)NB * 192 + (size_t)b * 192;
  float zt = sigm(az + bz[j] + Sr0[64 + j] + Sr1[64 + j] + bzmv[j]);
  ztl[r][j] = zt;
  __syncthreads();
  float aa = 0.f;
#pragma unroll 8
  for (int k = 0; k < DV; ++k) aa += ztl[r][k] * Wza[k * DV + j];
  float aval = tanhf(tanhf(aa + bza[j]) + tanhf(Sr0[128 + j] + Sr1[128 + j] + bamv[j]));
  float eval = sigm(sigm(ae + be[j]) + sigm(Sr0[j] + Sr1[j] + bemv[j]));
  eg[(size_t)b * DV + j] = eval;
  ag[(size_t)b * DV + j] = aval;
}

// ---------------------------------------------------------------------------
// K6: in-place elementwise on d_out:  out = mp*(1 - w*e) + w*a
// ---------------------------------------------------------------------------
__global__ __launch_bounds__(256) void k_final(float* __restrict__ mp,
                                               const float* __restrict__ ww,
                                               const float* __restrict__ eg,
                                               const float* __restrict__ ag) {
  const size_t idx8 = ((size_t)blockIdx.x * 256 + threadIdx.x) * 8;
  const int row = (int)(idx8 >> 12);
  const int colg = (int)(idx8 & 4095);
  const int mi = colg >> 6, j = colg & 63;
  const float w = ww[(size_t)row * MM + mi];
  const float4 e0 = *(const float4*)(eg + (size_t)row * DV + j);
  const float4 e1 = *(const float4*)(eg + (size_t)row * DV + j + 4);
  const float4 a0 = *(const float4*)(ag + (size_t)row * DV + j);
  const float4 a1 = *(const float4*)(ag + (size_t)row * DV + j + 4);
  float4 m0 = *(const float4*)(mp + idx8);
  float4 m1 = *(const float4*)(mp + idx8 + 4);
  m0.x = m0.x * (1.f - w * e0.x) + w * a0.x;
  m0.y = m0.y * (1.f - w * e0.y) + w * a0.y;
  m0.z = m0.z * (1.f - w * e0.z) + w * a0.z;
  m0.w = m0.w * (1.f - w * e0.w) + w * a0.w;
  m1.x = m1.x * (1.f - w * e1.x) + w * a1.x;
  m1.y = m1.y * (1.f - w * e1.y) + w * a1.y;
  m1.z = m1.z * (1.f - w * e1.z) + w * a1.z;
  m1.w = m1.w * (1.f - w * e1.w) + w * a1.w;
  *(float4*)(mp + idx8) = m0;
  *(float4*)(mp + idx8 + 4) = m1;
}

// ---------------------------------------------------------------------------
extern "C" void kernel_launch(void* const* d_in, const int* in_sizes, int n_in,
                              void* d_out, int out_size, void* d_ws, size_t ws_size,
                              hipStream_t stream) {
  const float* ck   = (const float*)d_in[0];
  const float* qa   = (const float*)d_in[1];
  const float* mk   = (const float*)d_in[2];
  const float* mv   = (const float*)d_in[3];
  const float* We   = (const float*)d_in[4];
  const float* be   = (const float*)d_in[5];
  const float* Wemv = (const float*)d_in[6];
  const float* bemv = (const float*)d_in[7];
  const float* Wza  = (const float*)d_in[8];
  const float* bza  = (const float*)d_in[9];
  const float* Wamv = (const float*)d_in[10];
  const float* bamv = (const float*)d_in[11];
  const float* Wc0  = (const float*)d_in[12];
  const float* bc0  = (const float*)d_in[13];
  const float* Wm1  = (const float*)d_in[14];
  const float* bm1  = (const float*)d_in[15];
  const float* Wz   = (const float*)d_in[16];
  const float* bz   = (const float*)d_in[17];
  const float* Wzmv = (const float*)d_in[18];
  const float* bzmv = (const float*)d_in[19];
  float* outp = (float*)d_out;

  // workspace carve (~45 MB)
  char* base = (char*)d_ws;
  float* wwp = (float*)base;                      base += (size_t)NB * MM * 4;
  unsigned short* c0p = (unsigned short*)base;    base += (size_t)NB * DQA * 2;
  float* Sp = (float*)base;                       base += (size_t)2 * NB * 192 * 4;
  float* ep = (float*)base;                       base += (size_t)NB * DV * 4;
  float* ap = (float*)base;                       base += (size_t)NB * DV * 4;
  unsigned short* WcT  = (unsigned short*)base;   base += (size_t)DQA * LDW * 2;
  unsigned short* Wm1T = (unsigned short*)base;   base += (size_t)MD * DQA * 2;
  unsigned short* W3T  = (unsigned short*)base;   base += (size_t)192 * LDW * 2;

  // c0 fp32 partials (2 x 8MB) aliased into d_out — free until k_g1mp writes it
  float* Pp = outp;

  // weight prep (bf16 + transpose; padded row stride LDW for the MD-wide ones)
  k_tr<<<dim3(MD / 64, DQA / 64), 256, 0, stream>>>(Wc0, WcT, DQA, LDW);
  k_tr<<<dim3(DQA / 64, MD / 64), 256, 0, stream>>>(Wm1, Wm1T, MD, DQA);
  k_tr<<<dim3(MD / 64, 1), 256, 0, stream>>>(Wemv, W3T, DV, LDW);
  k_tr<<<dim3(MD / 64, 1), 256, 0, stream>>>(Wzmv, W3T + (size_t)64 * LDW, DV, LDW);
  k_tr<<<dim3(MD / 64, 1), 256, 0, stream>>>(Wamv, W3T + (size_t)128 * LDW, DV, LDW);

  k_ww<<<NB / 4, 256, 0, stream>>>(ck, mk, wwp);
  k_c0<<<dim3(NB / 32, 2), 256, 0, stream>>>(mv, WcT, Pp);
  k_c0fin<<<(NB * DQA / 4) / 256, 256, 0, stream>>>(Pp, bc0, qa, c0p);
  k_g1mp<<<dim3(NB / 64, MD / 128), 256, 0, stream>>>(mv, c0p, Wm1T, bm1, outp);
  k_S<<<dim3(NB / 32, 2), 256, 0, stream>>>(outp, W3T, Sp);
  k_eza<<<NB / 4, 256, 0, stream>>>(c0p, Sp, We, be, Wz, bz, Wza, bza, bemv, bzmv, bamv, ep, ap);
  k_final<<<(NB * MD / 8) / 256, 256, 0, stream>>>(outp, wwp, ep, ap);
}

// Round 2
// 1011.574 us; speedup vs baseline: 1.1539x; 1.0352x over previous
//
#include <hip/hip_runtime.h>

// Problem constants
#define NB  16384   // batch
#define MM  64      // memory slots
#define DV  64
#define DK  64
#define DQA 128
#define MD  4096    // MM*DV
#define LDW 4224    // padded row stride (elements) for bf16 matrices (+256B -> channel rotation)

typedef float  floatx4 __attribute__((ext_vector_type(4)));
typedef short  shortx8 __attribute__((ext_vector_type(8)));
typedef unsigned short ushortx4 __attribute__((ext_vector_type(4)));

static __device__ __forceinline__ unsigned short f2bf(float f) {
  union { float f; unsigned int u; } v; v.f = f;
  unsigned int r = v.u + 0x7FFFu + ((v.u >> 16) & 1u);  // RNE
  return (unsigned short)(r >> 16);
}
static __device__ __forceinline__ float bf2f(unsigned short u) {
  union { unsigned int u; float f; } v; v.u = (unsigned int)u << 16; return v.f;
}
static __device__ __forceinline__ float sigm(float x) { return 1.0f / (1.0f + __expf(-x)); }

// ---------------------------------------------------------------------------
// k_tr: transpose+convert  src fp32 [K][N] (row-major, ld=N)  ->  dst bf16 [N][dstld]
// grid (K/64, N/64).
// ---------------------------------------------------------------------------
__global__ __launch_bounds__(256) void k_tr(const float* __restrict__ src,
                                            unsigned short* __restrict__ dst,
                                            int N, int dstld) {
  __shared__ unsigned short T[64 * 72];
  const int k0 = blockIdx.x * 64, n0 = blockIdx.y * 64;
  const int t = threadIdx.x;
#pragma unroll
  for (int i = 0; i < 16; ++i) {
    int idx = t + i * 256, kl = idx >> 6, nl = idx & 63;
    T[kl * 72 + nl] = f2bf(src[(size_t)(k0 + kl) * N + n0 + nl]);
  }
  __syncthreads();
#pragma unroll
  for (int i = 0; i < 16; ++i) {
    int idx = t + i * 256, nl = idx >> 6, kl = idx & 63;
    dst[(size_t)(n0 + nl) * dstld + k0 + kl] = T[kl * 72 + nl];
  }
}

// ---------------------------------------------------------------------------
// K1: write_weight = softmax(control_key @ memory_key^T).  One wave per row.
// ---------------------------------------------------------------------------
__global__ __launch_bounds__(256) void k_ww(const float* __restrict__ ck,
                                            const float* __restrict__ mk,
                                            float* __restrict__ ww) {
  const int t = threadIdx.x;
  const int lane = t & 63;
  const int wv = t >> 6;
  const int b = blockIdx.x * 4 + wv;
  const float4* ck4 = (const float4*)(ck + (size_t)b * DK);
  const float4* mk4 = (const float4*)(mk + (size_t)lane * DK);
  float s = 0.f;
#pragma unroll
  for (int i = 0; i < DK / 4; ++i) {
    float4 a = ck4[i], m = mk4[i];
    s += a.x * m.x + a.y * m.y + a.z * m.z + a.w * m.w;
  }
  float mx = s;
#pragma unroll
  for (int off = 32; off; off >>= 1) mx = fmaxf(mx, __shfl_xor(mx, off, 64));
  float e = __expf(s - mx);
  float sum = e;
#pragma unroll
  for (int off = 32; off; off >>= 1) sum += __shfl_xor(sum, off, 64);
  ww[(size_t)b * MM + lane] = e / sum;
}

// ---------------------------------------------------------------------------
// K2: partial pre-activation of c0:  P[split] = mv @ Wc0 over K-half "split".
// 512 threads (8 waves), M=64 rows/block.  A staged through LDS with dense
// coalesced fp32 loads (+convert);  B staged as 16B bf16 copies.
// Wave geometry: mh=wv&3 -> rows mh*16, nq=wv>>2 -> cols nq*64 (4 n-tiles).
// ---------------------------------------------------------------------------
__global__ __launch_bounds__(512, 4) void k_c0(const float* __restrict__ mv,
                                               const unsigned short* __restrict__ WcT,
                                               float* __restrict__ P) {
  __shared__ __align__(16) unsigned short WB[DQA * 136];   // [n<128][k<128 +8]
  __shared__ __align__(16) unsigned short AB[64 * 136];    // [m<64][k<128 +8]
  const int t = threadIdx.x, lane = t & 63, wv = t >> 6;
  const int quad = lane >> 4, l16 = lane & 15;
  const int mh = wv & 3, nq = wv >> 2;
  const int rowbase = blockIdx.x * 64;
  const int split = blockIdx.y;

  floatx4 acc[4];
#pragma unroll
  for (int nt = 0; nt < 4; ++nt) acc[nt] = (floatx4){0.f, 0.f, 0.f, 0.f};

  for (int c = 0; c < 16; ++c) {
    const int kc = split * 16 + ((c + blockIdx.x) & 15);
    const int kb = kc * 128;
    // stage A: 64 rows x 128 cols fp32 -> bf16 LDS (dense 16B loads)
#pragma unroll
    for (int p = 0; p < 4; ++p) {
      int row = p * 16 + (t >> 5);
      int col4 = (t & 31) * 4;
      float4 v = *(const float4*)(mv + (size_t)(rowbase + row) * MD + kb + col4);
      ushortx4 o;
      o[0] = f2bf(v.x); o[1] = f2bf(v.y); o[2] = f2bf(v.z); o[3] = f2bf(v.w);
      *(ushortx4*)&AB[row * 136 + col4] = o;
    }
    // stage B: 128 rows x 128 cols bf16 (pure 16B copies)
#pragma unroll
    for (int p = 0; p < 4; ++p) {
      int idx = t + p * 512;        // 0..2047
      int n = idx >> 4, kbk = idx & 15;
      *(shortx8*)&WB[n * 136 + kbk * 8] =
          *(const shortx8*)(WcT + (size_t)n * LDW + kb + kbk * 8);
    }
    __syncthreads();
    shortx8 afr[4];
#pragma unroll
    for (int ks = 0; ks < 4; ++ks)
      afr[ks] = *(const shortx8*)&AB[(mh * 16 + l16) * 136 + ks * 32 + quad * 8];
#pragma unroll
    for (int nt = 0; nt < 4; ++nt)
#pragma unroll
      for (int ks = 0; ks < 4; ++ks) {
        shortx8 bfr = *(const shortx8*)&WB[(nq * 64 + nt * 16 + l16) * 136 + ks * 32 + quad * 8];
        acc[nt] = __builtin_amdgcn_mfma_f32_16x16x32_bf16(afr[ks], bfr, acc[nt], 0, 0, 0);
      }
    __syncthreads();
  }
  float* Pp = P + (size_t)split * NB * DQA;
#pragma unroll
  for (int nt = 0; nt < 4; ++nt) {
    int col = nq * 64 + nt * 16 + l16;
#pragma unroll
    for (int r = 0; r < 4; ++r) {
      int row = rowbase + mh * 16 + quad * 4 + r;
      Pp[(size_t)row * DQA + col] = acc[nt][r];
    }
  }
}

// ---------------------------------------------------------------------------
// K2b: combine the two K-halves, apply bias+sigmoid+qa, store bf16 c0.
// ---------------------------------------------------------------------------
__global__ __launch_bounds__(256) void k_c0fin(const float* __restrict__ P,
                                               const float* __restrict__ bc0,
                                               const float* __restrict__ qa,
                                               unsigned short* __restrict__ c0p) {
  const size_t i4 = ((size_t)blockIdx.x * 256 + threadIdx.x) * 4;
  const int col = (int)(i4 & (DQA - 1));
  float4 p0 = *(const float4*)(P + i4);
  float4 p1 = *(const float4*)(P + (size_t)NB * DQA + i4);
  float4 b  = *(const float4*)(bc0 + col);
  float4 q  = *(const float4*)(qa + i4);
  ushortx4 o;
  o[0] = f2bf(q.x * sigm(p0.x + p1.x + b.x));
  o[1] = f2bf(q.y * sigm(p0.y + p1.y + b.y));
  o[2] = f2bf(q.z * sigm(p0.z + p1.z + b.z));
  o[3] = f2bf(q.w * sigm(p0.w + p1.w + b.w));
  *(ushortx4*)(c0p + i4) = o;
}

// ---------------------------------------------------------------------------
// K3: gate1 chunk via MFMA; mp = mv * g1 written fp32 into d_out (and bf16
// padded into mpb when usebf).  Vectorized epilogue via LDS acc transpose.
// Grid (NB/64, MD/128), 256 thr.
// ---------------------------------------------------------------------------
__global__ __launch_bounds__(256) void k_g1mp(const float* __restrict__ mv,
                                              const unsigned short* __restrict__ c0p,
                                              const unsigned short* __restrict__ Wm1T,
                                              const float* __restrict__ bm1,
                                              float* __restrict__ mp,
                                              unsigned short* __restrict__ mpb,
                                              int usebf) {
  __shared__ __align__(16) unsigned char SM[128 * 136 * 2];   // 34816 B
  unsigned short* WB = (unsigned short*)SM;                   // [128][136]
  float* Tf = (float*)SM;                                     // [64][132] (33792 B)
  const int t = threadIdx.x, lane = t & 63, wv = t >> 6;
  const int quad = lane >> 4, l16 = lane & 15;
  const int rowbase = blockIdx.x * 64;
  const int colbase = blockIdx.y * 128;

  // c0 A-fragments (full K=128)
  shortx8 c0fr[4];
#pragma unroll
  for (int ks = 0; ks < 4; ++ks)
    c0fr[ks] = *(const shortx8*)(c0p + (size_t)(rowbase + wv * 16 + l16) * DQA + ks * 32 + quad * 8);

  // stage Wm1T rows [colbase..colbase+128), full K=128
#pragma unroll
  for (int i = 0; i < 8; ++i) {
    int idx = t + i * 256;
    int n = idx >> 4, kbk = idx & 15;
    *(shortx8*)&WB[n * 136 + kbk * 8] =
        *(const shortx8*)(Wm1T + (size_t)(colbase + n) * DQA + kbk * 8);
  }
  __syncthreads();

  floatx4 acc[8];
#pragma unroll
  for (int nt = 0; nt < 8; ++nt) acc[nt] = (floatx4){0.f, 0.f, 0.f, 0.f};
#pragma unroll
  for (int nt = 0; nt < 8; ++nt)
#pragma unroll
    for (int ks = 0; ks < 4; ++ks) {
      shortx8 bfr = *(const shortx8*)&WB[(nt * 16 + l16) * 136 + ks * 32 + quad * 8];
      acc[nt] = __builtin_amdgcn_mfma_f32_16x16x32_bf16(c0fr[ks], bfr, acc[nt], 0, 0, 0);
    }

  __syncthreads();   // all WB reads done; reuse LDS as fp32 acc tile
#pragma unroll
  for (int nt = 0; nt < 8; ++nt)
#pragma unroll
    for (int r = 0; r < 4; ++r)
      Tf[(wv * 16 + quad * 4 + r) * 132 + nt * 16 + l16] = acc[nt][r];
  __syncthreads();

  // vectorized epilogue: each thread owns 32 contiguous cols of one row
  const int row = t >> 2;
  const int colq = (t & 3) * 32;
  const float* mvp = mv + (size_t)(rowbase + row) * MD + colbase + colq;
  float* mpp = mp + (size_t)(rowbase + row) * MD + colbase + colq;
  const float* bmp = bm1 + colbase + colq;
  unsigned short tb[32];
#pragma unroll
  for (int i = 0; i < 8; ++i) {
    float4 g4 = *(const float4*)&Tf[row * 132 + colq + i * 4];
    float4 b4 = *(const float4*)(bmp + i * 4);
    float4 m4 = *(const float4*)(mvp + i * 4);
    float4 o;
    o.x = m4.x * sigm(g4.x + b4.x);
    o.y = m4.y * sigm(g4.y + b4.y);
    o.z = m4.z * sigm(g4.z + b4.z);
    o.w = m4.w * sigm(g4.w + b4.w);
    *(float4*)(mpp + i * 4) = o;
    tb[i * 4 + 0] = f2bf(o.x); tb[i * 4 + 1] = f2bf(o.y);
    tb[i * 4 + 2] = f2bf(o.z); tb[i * 4 + 3] = f2bf(o.w);
  }
  if (usebf) {
    unsigned short* mbp = mpb + (size_t)(rowbase + row) * LDW + colbase + colq;
#pragma unroll
    for (int j = 0; j < 4; ++j)
      *(shortx8*)(mbp + j * 8) = *(const shortx8*)&tb[j * 8];
  }
}

// ---------------------------------------------------------------------------
// K4: partial S[16384 x 192] = mp @ [WemvT|WzmvT|WamvT]^T over K-half "split".
// 512 threads (8 waves), M=64 rows/block.  A staged via LDS (bf16 16B copies
// from mpb when usebf; else dense fp32 loads from mp + convert).
// Wave geometry: mh=wv&3 -> rows mh*16, nh=wv>>2 -> cols nh*96 (6 n-tiles).
// ---------------------------------------------------------------------------
__global__ __launch_bounds__(512, 4) void k_S(const float* __restrict__ mp32,
                                              const unsigned short* __restrict__ mpb,
                                              const unsigned short* __restrict__ W3T,
                                              float* __restrict__ Sg,
                                              int usebf) {
  __shared__ __align__(16) unsigned short WB[192 * 136];   // [n<192][k<128 +8]
  __shared__ __align__(16) unsigned short AB[64 * 136];    // [m<64][k<128 +8]
  const int t = threadIdx.x, lane = t & 63, wv = t >> 6;
  const int quad = lane >> 4, l16 = lane & 15;
  const int mh = wv & 3, nh = wv >> 2;
  const int rowbase = blockIdx.x * 64;
  const int split = blockIdx.y;

  floatx4 acc[6];
#pragma unroll
  for (int nt = 0; nt < 6; ++nt) acc[nt] = (floatx4){0.f, 0.f, 0.f, 0.f};

  for (int c = 0; c < 16; ++c) {
    const int kc = split * 16 + ((c + blockIdx.x) & 15);
    const int kb = kc * 128;
    if (usebf) {
      // A: pure 16B bf16 copies, padded-stride source
#pragma unroll
      for (int p = 0; p < 2; ++p) {
        int row = p * 32 + (t >> 4);
        int col8 = (t & 15) * 8;
        *(shortx8*)&AB[row * 136 + col8] =
            *(const shortx8*)(mpb + (size_t)(rowbase + row) * LDW + kb + col8);
      }
    } else {
      // A: dense fp32 loads + convert
#pragma unroll
      for (int p = 0; p < 4; ++p) {
        int row = p * 16 + (t >> 5);
        int col4 = (t & 31) * 4;
        float4 v = *(const float4*)(mp32 + (size_t)(rowbase + row) * MD + kb + col4);
        ushortx4 o;
        o[0] = f2bf(v.x); o[1] = f2bf(v.y); o[2] = f2bf(v.z); o[3] = f2bf(v.w);
        *(ushortx4*)&AB[row * 136 + col4] = o;
      }
    }
    // stage B: 192 rows x 128 cols bf16
#pragma unroll
    for (int p = 0; p < 6; ++p) {
      int idx = t + p * 512;        // 0..3071
      int n = idx >> 4, kbk = idx & 15;
      *(shortx8*)&WB[n * 136 + kbk * 8] =
          *(const shortx8*)(W3T + (size_t)n * LDW + kb + kbk * 8);
    }
    __syncthreads();
    shortx8 afr[4];
#pragma unroll
    for (int ks = 0; ks < 4; ++ks)
      afr[ks] = *(const shortx8*)&AB[(mh * 16 + l16) * 136 + ks * 32 + quad * 8];
#pragma unroll
    for (int nt = 0; nt < 6; ++nt)
#pragma unroll
      for (int ks = 0; ks < 4; ++ks) {
        shortx8 bfr = *(const shortx8*)&WB[(nh * 96 + nt * 16 + l16) * 136 + ks * 32 + quad * 8];
        acc[nt] = __builtin_amdgcn_mfma_f32_16x16x32_bf16(afr[ks], bfr, acc[nt], 0, 0, 0);
      }
    __syncthreads();
  }
  float* Sp = Sg + (size_t)split * NB * 192;
#pragma unroll
  for (int nt = 0; nt < 6; ++nt) {
    int col = nh * 96 + nt * 16 + l16;
#pragma unroll
    for (int r = 0; r < 4; ++r) {
      int row = rowbase + mh * 16 + quad * 4 + r;
      Sp[(size_t)row * 192 + col] = acc[nt][r];
    }
  }
}

// ---------------------------------------------------------------------------
// K5: finalize erase / zt / add  (small GEMMs, fp32 VALU).  Block = 4 rows x 64.
// Sums the two K-half partials of S.
// ---------------------------------------------------------------------------
__global__ __launch_bounds__(256) void k_eza(const unsigned short* __restrict__ c0p,
                                             const float* __restrict__ Sg,
                                             const float* __restrict__ We,
                                             const float* __restrict__ be,
                                             const float* __restrict__ Wz,
                                             const float* __restrict__ bz,
                                             const float* __restrict__ Wza,
                                             const float* __restrict__ bza,
                                             const float* __restrict__ bemv,
                                             const float* __restrict__ bzmv,
                                             const float* __restrict__ bamv,
                                             float* __restrict__ eg,
                                             float* __restrict__ ag) {
  __shared__ float ztl[4][64];
  const int t = threadIdx.x;
  const int j = t & 63;
  const int r = t >> 6;
  const int b = blockIdx.x * 4 + r;
  const unsigned short* c0r = c0p + (size_t)b * DQA;
  float ae = 0.f, az = 0.f;
#pragma unroll 8
  for (int k = 0; k < DQA; ++k) {
    float cv = bf2f(c0r[k]);
    ae += cv * We[k * DV + j];
    az += cv * Wz[k * DV + j];
  }
  const float* Sr0 = Sg + (size_t)b * 192;
  const float* Sr1 = Sg + (size_t)NB * 192 + (size_t)b * 192;
  float zt = sigm(az + bz[j] + Sr0[64 + j] + Sr1[64 + j] + bzmv[j]);
  ztl[r][j] = zt;
  __syncthreads();
  float aa = 0.f;
#pragma unroll 8
  for (int k = 0; k < DV; ++k) aa += ztl[r][k] * Wza[k * DV + j];
  float aval = tanhf(tanhf(aa + bza[j]) + tanhf(Sr0[128 + j] + Sr1[128 + j] + bamv[j]));
  float eval = sigm(sigm(ae + be[j]) + sigm(Sr0[j] + Sr1[j] + bemv[j]));
  eg[(size_t)b * DV + j] = eval;
  ag[(size_t)b * DV + j] = aval;
}

// ---------------------------------------------------------------------------
// K6: in-place elementwise on d_out:  out = mp*(1 - w*e) + w*a
// ---------------------------------------------------------------------------
__global__ __launch_bounds__(256) void k_final(float* __restrict__ mp,
                                               const float* __restrict__ ww,
                                               const float* __restrict__ eg,
                                               const float* __restrict__ ag) {
  const size_t idx8 = ((size_t)blockIdx.x * 256 + threadIdx.x) * 8;
  const int row = (int)(idx8 >> 12);
  const int colg = (int)(idx8 & 4095);
  const int mi = colg >> 6, j = colg & 63;
  const float w = ww[(size_t)row * MM + mi];
  const float4 e0 = *(const float4*)(eg + (size_t)row * DV + j);
  const float4 e1 = *(const float4*)(eg + (size_t)row * DV + j + 4);
  const float4 a0 = *(const float4*)(ag + (size_t)row * DV + j);
  const float4 a1 = *(const float4*)(ag + (size_t)row * DV + j + 4);
  float4 m0 = *(const float4*)(mp + idx8);
  float4 m1 = *(const float4*)(mp + idx8 + 4);
  m0.x = m0.x * (1.f - w * e0.x) + w * a0.x;
  m0.y = m0.y * (1.f - w * e0.y) + w * a0.y;
  m0.z = m0.z * (1.f - w * e0.z) + w * a0.z;
  m0.w = m0.w * (1.f - w * e0.w) + w * a0.w;
  m1.x = m1.x * (1.f - w * e1.x) + w * a1.x;
  m1.y = m1.y * (1.f - w * e1.y) + w * a1.y;
  m1.z = m1.z * (1.f - w * e1.z) + w * a1.z;
  m1.w = m1.w * (1.f - w * e1.w) + w * a1.w;
  *(float4*)(mp + idx8) = m0;
  *(float4*)(mp + idx8 + 4) = m1;
}

// ---------------------------------------------------------------------------
extern "C" void kernel_launch(void* const* d_in, const int* in_sizes, int n_in,
                              void* d_out, int out_size, void* d_ws, size_t ws_size,
                              hipStream_t stream) {
  const float* ck   = (const float*)d_in[0];
  const float* qa   = (const float*)d_in[1];
  const float* mk   = (const float*)d_in[2];
  const float* mv   = (const float*)d_in[3];
  const float* We   = (const float*)d_in[4];
  const float* be   = (const float*)d_in[5];
  const float* Wemv = (const float*)d_in[6];
  const float* bemv = (const float*)d_in[7];
  const float* Wza  = (const float*)d_in[8];
  const float* bza  = (const float*)d_in[9];
  const float* Wamv = (const float*)d_in[10];
  const float* bamv = (const float*)d_in[11];
  const float* Wc0  = (const float*)d_in[12];
  const float* bc0  = (const float*)d_in[13];
  const float* Wm1  = (const float*)d_in[14];
  const float* bm1  = (const float*)d_in[15];
  const float* Wz   = (const float*)d_in[16];
  const float* bz   = (const float*)d_in[17];
  const float* Wzmv = (const float*)d_in[18];
  const float* bzmv = (const float*)d_in[19];
  float* outp = (float*)d_out;

  // workspace carve
  char* base = (char*)d_ws;
  float* wwp = (float*)base;                      base += (size_t)NB * MM * 4;
  unsigned short* c0p = (unsigned short*)base;    base += (size_t)NB * DQA * 2;
  float* Sp = (float*)base;                       base += (size_t)2 * NB * 192 * 4;
  float* ep = (float*)base;                       base += (size_t)NB * DV * 4;
  float* ap = (float*)base;                       base += (size_t)NB * DV * 4;
  unsigned short* WcT  = (unsigned short*)base;   base += (size_t)DQA * LDW * 2;
  unsigned short* Wm1T = (unsigned short*)base;   base += (size_t)MD * DQA * 2;
  unsigned short* W3T  = (unsigned short*)base;   base += (size_t)192 * LDW * 2;
  unsigned short* mpb  = (unsigned short*)base;   // NB*LDW*2 = 138.4 MB if it fits
  size_t needed = (size_t)(base - (char*)d_ws) + (size_t)NB * LDW * 2;
  const int usebf = (ws_size >= needed) ? 1 : 0;

  // c0 fp32 partials (2 x 8MB) aliased into d_out — free until k_g1mp writes it
  float* Pp = outp;

  // weight prep (bf16 + transpose; padded row stride LDW for the MD-wide ones)
  k_tr<<<dim3(MD / 64, DQA / 64), 256, 0, stream>>>(Wc0, WcT, DQA, LDW);
  k_tr<<<dim3(DQA / 64, MD / 64), 256, 0, stream>>>(Wm1, Wm1T, MD, DQA);
  k_tr<<<dim3(MD / 64, 1), 256, 0, stream>>>(Wemv, W3T, DV, LDW);
  k_tr<<<dim3(MD / 64, 1), 256, 0, stream>>>(Wzmv, W3T + (size_t)64 * LDW, DV, LDW);
  k_tr<<<dim3(MD / 64, 1), 256, 0, stream>>>(Wamv, W3T + (size_t)128 * LDW, DV, LDW);

  k_ww<<<NB / 4, 256, 0, stream>>>(ck, mk, wwp);
  k_c0<<<dim3(NB / 64, 2), 512, 0, stream>>>(mv, WcT, Pp);
  k_c0fin<<<(NB * DQA / 4) / 256, 256, 0, stream>>>(Pp, bc0, qa, c0p);
  k_g1mp<<<dim3(NB / 64, MD / 128), 256, 0, stream>>>(mv, c0p, Wm1T, bm1, outp, mpb, usebf);
  k_S<<<dim3(NB / 64, 2), 512, 0, stream>>>(outp, mpb, W3T, Sp, usebf);
  k_eza<<<NB / 4, 256, 0, stream>>>(c0p, Sp, We, be, Wz, bz, Wza, bza, bemv, bzmv, bamv, ep, ap);
  k_final<<<(NB * MD / 8) / 256, 256, 0, stream>>>(outp, wwp, ep, ap);
}